// Round 2
// baseline (269.357 us; speedup 1.0000x reference)
//
#include <hip/hip_runtime.h>
#include <hip/hip_bf16.h>

using bf16 = __hip_bfloat16;
typedef __bf16 bf16x8 __attribute__((ext_vector_type(8)));
typedef float f32x4 __attribute__((ext_vector_type(4)));

#define MFMA16(a, b, c) __builtin_amdgcn_mfma_f32_16x16x32_bf16((a), (b), (c), 0, 0, 0)

// Problem: N=65536, P=6, D=256, IN=17 (pad->32), RAW=20, occ=1 (pad cols->32)
// out=(N, 27) fp32.  ALL float tensors are fp32 (per reference); compute in
// bf16 MFMA with fp32 accumulation, biases added in fp32 (exact).
//
// ws layout (bf16 elements):
//   W1t [P][256 n][32 k]  @ 0       (49152)   W1t[p][n][k] = k<17 ? W1[p][k][n] : 0
//   W2t [P][256 n][256 k] @ 49152   (393216)  W2t[p][n][k] = W2[p][k][n]
//   W3t [P][32 n][256 k]  @ 442368  (49152)   n<20: W3[p][k][n]; n==20: Wocc[p][k]; else 0

__global__ void prep_kernel(const float* __restrict__ W1, const float* __restrict__ W2,
                            const float* __restrict__ W3, const float* __restrict__ Wocc,
                            bf16* __restrict__ ws) {
  int t = blockIdx.x * 256 + threadIdx.x;
  if (t < 49152) {                       // W1t
    int p = t >> 13, r = t & 8191, n = r >> 5, k = r & 31;
    ws[t] = __float2bfloat16((k < 17) ? W1[p * 4352 + k * 256 + n] : 0.f);
  } else if (t < 442368) {               // W2t
    int u = t - 49152;
    int p = u >> 16, r = u & 65535, n = r >> 8, k = r & 255;
    ws[t] = __float2bfloat16(W2[p * 65536 + k * 256 + n]);
  } else if (t < 491520) {               // W3t (W3 || Wocc || zeros)
    int u = t - 442368;
    int p = u >> 13, r = u & 8191, n = r >> 8, k = r & 255;
    float v = 0.f;
    if (n < 20)       v = W3[p * 5120 + k * 20 + n];
    else if (n == 20) v = Wocc[p * 256 + k];
    ws[t] = __float2bfloat16(v);
  }
}

// Block: 256 threads (4 waves), 64 rows. Waves partition columns (64 each) for
// L1/L2; wave w owns row-tile mt=w for L3. X (A-frag order, 4KB) and H (A-frag
// order, 32KB) in LDS; B fragments (W1t/W2t/W3t) loaded straight from global
// (L2-resident, zero cross-wave reuse -> LDS staging would be pure overhead).
// 4 barriers per part.
__global__ __launch_bounds__(256, 2) void tpose_main(
    const float* __restrict__ tpts, const float* __restrict__ bigpts,
    const float* __restrict__ viewdir, const float* __restrict__ frame,
    const float* __restrict__ b1g, const float* __restrict__ b2g,
    const float* __restrict__ b3g, const float* __restrict__ boccg,
    const int* __restrict__ tflag, const bf16* __restrict__ ws,
    float* __restrict__ out) {
  const bf16* __restrict__ W1t = ws;
  const bf16* __restrict__ W2t = ws + 49152;
  const bf16* __restrict__ W3t = ws + 442368;

  __shared__ __align__(16) bf16 Xf[2048];   // 4 mt * 64 lanes * 8 (A-frag order)
  __shared__ __align__(16) bf16 Hf[16384];  // 32 (mt*8+kk) slots * 64 lanes * 8

  const int tid = threadIdx.x;
  const int w = tid >> 6;
  const int lane = tid & 63;
  const int lq = lane >> 4;   // quad 0..3
  const int ln = lane & 15;   // n/col within 16-tile
  const int n0 = blockIdx.x * 64;

  float psum0[4] = {0.f, 0.f, 0.f, 0.f};  // cols 0..15 (raw)
  float psum1[4] = {0.f, 0.f, 0.f, 0.f};  // cols 16..20 (raw 16-19, occ 20)

  const int xm = tid >> 2;  // row 0..63 for X build
  const int xq = tid & 3;   // k-octet 0..3

  for (int p = 0; p < 6; ++p) {
    // ---------- Phase A: build X tile (fp32 -> bf16) in A-fragment order ----
    {
      const int base3 = ((n0 + xm) * 6 + p) * 3;
      bf16x8 xv;
#pragma unroll
      for (int j = 0; j < 8; ++j) {
        const int k = xq * 8 + j;
        float v;
        if (k < 3)       v = tpts[base3 + k];
        else if (k < 11) v = frame[k - 3];
        else if (k < 14) v = bigpts[base3 + (k - 11)];
        else if (k < 17) v = viewdir[base3 + (k - 14)];
        else             v = 0.f;
        xv[j] = (__bf16)v;
      }
      const int mt = xm >> 4;
      const int lr = (xm & 15) + xq * 16;
      *reinterpret_cast<bf16x8*>(&Xf[(mt * 64 + lr) * 8]) = xv;
    }

    float b1v[4], b2v[4];
#pragma unroll
    for (int nt = 0; nt < 4; ++nt) {
      const int d = w * 64 + nt * 16 + ln;
      b1v[nt] = b1g[p * 256 + d];
      b2v[nt] = b2g[p * 256 + d];
    }
    const float b3e0 = b3g[p * 20 + ln];  // ln<16 => col<20
    float b3e1 = 0.f;
    if (ln < 4)       b3e1 = b3g[p * 20 + 16 + ln];
    else if (ln == 4) b3e1 = boccg[p];

    __syncthreads();  // (1) X visible

    // ---------- Phase B: H1 = relu(X @ W1 + b1) ----------
    f32x4 acc1[4][4];
#pragma unroll
    for (int mt = 0; mt < 4; ++mt)
#pragma unroll
      for (int nt = 0; nt < 4; ++nt) acc1[mt][nt] = f32x4{0.f, 0.f, 0.f, 0.f};

    {
      bf16x8 bw[4];
#pragma unroll
      for (int nt = 0; nt < 4; ++nt)
        bw[nt] = *reinterpret_cast<const bf16x8*>(
            &W1t[p * 8192 + (w * 64 + nt * 16 + ln) * 32 + lq * 8]);
#pragma unroll
      for (int mt = 0; mt < 4; ++mt) {
        const bf16x8 a = *reinterpret_cast<const bf16x8*>(&Xf[(mt * 64 + lane) * 8]);
#pragma unroll
        for (int nt = 0; nt < 4; ++nt) acc1[mt][nt] = MFMA16(a, bw[nt], acc1[mt][nt]);
      }
    }

#pragma unroll
    for (int mt = 0; mt < 4; ++mt)
#pragma unroll
      for (int nt = 0; nt < 4; ++nt) {
        const int d = w * 64 + nt * 16 + ln;
#pragma unroll
        for (int r = 0; r < 4; ++r) {
          float v = fmaxf(acc1[mt][nt][r] + b1v[nt], 0.f);
          const int lr = (lq * 4 + r) + ((d & 31) >> 3) * 16;
          Hf[(mt * 8 + (d >> 5)) * 512 + lr * 8 + (d & 7)] = __float2bfloat16(v);
        }
      }

    __syncthreads();  // (2) H1 visible

    // ---------- Phase C: H2 = relu(H1 @ W2 + b2), K-loop, no barriers ------
    f32x4 acc2[4][4];
#pragma unroll
    for (int mt = 0; mt < 4; ++mt)
#pragma unroll
      for (int nt = 0; nt < 4; ++nt) acc2[mt][nt] = f32x4{0.f, 0.f, 0.f, 0.f};

    const bf16* __restrict__ w2p = W2t + p * 65536 + (w * 64 + ln) * 256 + lq * 8;
#pragma unroll
    for (int kk = 0; kk < 8; ++kk) {
      bf16x8 bw[4];
#pragma unroll
      for (int nt = 0; nt < 4; ++nt)
        bw[nt] = *reinterpret_cast<const bf16x8*>(w2p + nt * 4096 + kk * 32);
#pragma unroll
      for (int mt = 0; mt < 4; ++mt) {
        const bf16x8 a =
            *reinterpret_cast<const bf16x8*>(&Hf[(mt * 8 + kk) * 512 + lane * 8]);
#pragma unroll
        for (int nt = 0; nt < 4; ++nt) acc2[mt][nt] = MFMA16(a, bw[nt], acc2[mt][nt]);
      }
    }

    __syncthreads();  // (3) all H1 reads done before overwrite

#pragma unroll
    for (int mt = 0; mt < 4; ++mt)
#pragma unroll
      for (int nt = 0; nt < 4; ++nt) {
        const int d = w * 64 + nt * 16 + ln;
#pragma unroll
        for (int r = 0; r < 4; ++r) {
          float v = fmaxf(acc2[mt][nt][r] + b2v[nt], 0.f);
          const int lr = (lq * 4 + r) + ((d & 31) >> 3) * 16;
          Hf[(mt * 8 + (d >> 5)) * 512 + lr * 8 + (d & 7)] = __float2bfloat16(v);
        }
      }

    __syncthreads();  // (4) H2 visible

    // ---------- Phase D: L3 (raw||occ), wave w owns row-tile mt=w ----------
    f32x4 acc3[2];
    acc3[0] = f32x4{0.f, 0.f, 0.f, 0.f};
    acc3[1] = f32x4{0.f, 0.f, 0.f, 0.f};
    const bf16* __restrict__ w3p = W3t + p * 8192 + ln * 256 + lq * 8;
#pragma unroll
    for (int kk = 0; kk < 8; ++kk) {
      const bf16x8 a =
          *reinterpret_cast<const bf16x8*>(&Hf[(w * 8 + kk) * 512 + lane * 8]);
#pragma unroll
      for (int nt = 0; nt < 2; ++nt) {
        const bf16x8 bw3 =
            *reinterpret_cast<const bf16x8*>(w3p + nt * 4096 + kk * 32);
        acc3[nt] = MFMA16(a, bw3, acc3[nt]);
      }
    }

    // Epilogue: flag-masked accumulation + tocc store (fp32 out)
#pragma unroll
    for (int r = 0; r < 4; ++r) {
      const int nrow = n0 + w * 16 + lq * 4 + r;
      const float fl = (tflag[nrow * 6 + p] != 0) ? 1.f : 0.f;
      psum0[r] += fl * (acc3[0][r] + b3e0);
      const float v1 = acc3[1][r] + b3e1;
      if (ln == 4) {  // col 20 = occ
        const float occ = 1.f / (1.f + __expf(-v1));
        out[nrow * 27 + 21 + p] = fl * occ;
        psum1[r] += fl * occ;
      } else if (ln < 4) {  // cols 16..19 raw
        psum1[r] += fl * v1;
      }
    }
  }  // p loop

  // mean over P=6 (zeros included per reference)
  const float inv6 = 1.f / 6.f;
#pragma unroll
  for (int r = 0; r < 4; ++r) {
    const int nrow = n0 + w * 16 + lq * 4 + r;
    out[nrow * 27 + ln] = psum0[r] * inv6;
    if (ln < 5) out[nrow * 27 + 16 + ln] = psum1[r] * inv6;
  }
}

extern "C" void kernel_launch(void* const* d_in, const int* in_sizes, int n_in,
                              void* d_out, int out_size, void* d_ws, size_t ws_size,
                              hipStream_t stream) {
  const float* tpts    = (const float*)d_in[0];
  const float* bigpts  = (const float*)d_in[1];
  const float* viewdir = (const float*)d_in[2];
  // d_in[3] dists, d_in[4] part_dist: unused by the reference
  const float* frame   = (const float*)d_in[5];
  const float* W1      = (const float*)d_in[6];
  const float* b1      = (const float*)d_in[7];
  const float* W2      = (const float*)d_in[8];
  const float* b2      = (const float*)d_in[9];
  const float* W3      = (const float*)d_in[10];
  const float* b3      = (const float*)d_in[11];
  const float* Wocc    = (const float*)d_in[12];
  const float* bocc    = (const float*)d_in[13];
  const int*   tflag   = (const int*)d_in[14];
  bf16*  ws  = (bf16*)d_ws;
  float* out = (float*)d_out;

  // 491520 ws elements = 983040 bytes needed
  prep_kernel<<<1920, 256, 0, stream>>>(W1, W2, W3, Wocc, ws);
  tpose_main<<<1024, 256, 0, stream>>>(tpts, bigpts, viewdir, frame, b1, b2, b3,
                                       bocc, tflag, ws, out);
}